// Round 2
// baseline (57.335 us; speedup 1.0000x reference)
//
#include <hip/hip_runtime.h>
#include <math.h>

constexpr int kD   = 128;
constexpr int kE   = 256;
constexpr int kTok = 2048;

// ---------------- K1: gate (logits -> softmax -> top2 -> lists) -------------
// 512 blocks x 256 threads; block handles 4 tokens; thread t = expert t.
__global__ __launch_bounds__(256) void k_gate(
    const float* __restrict__ x, const float* __restrict__ gate_w,
    const float* __restrict__ gate_b,
    float2* __restrict__ tokinfo, int* __restrict__ counts,
    int* __restrict__ lists, int cap)
{
    const int b  = blockIdx.x;
    const int t  = threadIdx.x;
    const int wv = t >> 6, ln = t & 63;

    __shared__ float xsT[kD][4];      // transposed x tile
    __shared__ float partf[4][4];     // [wave][token]
    __shared__ int   parti[4][4];
    __shared__ int   pi0s[4];

    // wave wv loads token wv's row (float2 per lane)
    {
        const float2 v = *(const float2*)(x + ((size_t)(b * 4 + wv)) * kD + ln * 2);
        xsT[ln * 2 + 0][wv] = v.x;
        xsT[ln * 2 + 1][wv] = v.y;
    }
    __syncthreads();

    // logits: 4 tokens per thread
    float lg[4];
    {
        const float bias = gate_b[t];
        lg[0] = lg[1] = lg[2] = lg[3] = bias;
    }
    #pragma unroll 8
    for (int d = 0; d < kD; ++d) {
        const float w = gate_w[d * kE + t];
        const float4 xv = *(const float4*)&xsT[d][0];
        lg[0] = fmaf(xv.x, w, lg[0]);
        lg[1] = fmaf(xv.y, w, lg[1]);
        lg[2] = fmaf(xv.z, w, lg[2]);
        lg[3] = fmaf(xv.w, w, lg[3]);
    }

    // ---- max over 256 experts (wave butterfly + 4-partial LDS) ----
    float m[4];
    #pragma unroll
    for (int j = 0; j < 4; ++j) m[j] = lg[j];
    #pragma unroll
    for (int s = 1; s < 64; s <<= 1) {
        #pragma unroll
        for (int j = 0; j < 4; ++j) m[j] = fmaxf(m[j], __shfl_xor(m[j], s));
    }
    if (ln == 0) {
        #pragma unroll
        for (int j = 0; j < 4; ++j) partf[wv][j] = m[j];
    }
    __syncthreads();
    float mx[4];
    #pragma unroll
    for (int j = 0; j < 4; ++j)
        mx[j] = fmaxf(fmaxf(partf[0][j], partf[1][j]), fmaxf(partf[2][j], partf[3][j]));
    __syncthreads();

    // ---- sum of exp ----
    float ex[4], sm[4];
    #pragma unroll
    for (int j = 0; j < 4; ++j) { ex[j] = __expf(lg[j] - mx[j]); sm[j] = ex[j]; }
    #pragma unroll
    for (int s = 1; s < 64; s <<= 1) {
        #pragma unroll
        for (int j = 0; j < 4; ++j) sm[j] += __shfl_xor(sm[j], s);
    }
    if (ln == 0) {
        #pragma unroll
        for (int j = 0; j < 4; ++j) partf[wv][j] = sm[j];
    }
    __syncthreads();
    float p[4];
    #pragma unroll
    for (int j = 0; j < 4; ++j) {
        const float tot = partf[0][j] + partf[1][j] + partf[2][j] + partf[3][j];
        p[j] = ex[j] / tot;
    }
    __syncthreads();

    // ---- argmax pass 1 ----
    float v[4]; int ix[4];
    #pragma unroll
    for (int j = 0; j < 4; ++j) { v[j] = p[j]; ix[j] = t; }
    #pragma unroll
    for (int s = 1; s < 64; s <<= 1) {
        #pragma unroll
        for (int j = 0; j < 4; ++j) {
            const float ov = __shfl_xor(v[j], s);
            const int   oi = __shfl_xor(ix[j], s);
            if (ov > v[j] || (ov == v[j] && oi < ix[j])) { v[j] = ov; ix[j] = oi; }
        }
    }
    if (ln == 0) {
        #pragma unroll
        for (int j = 0; j < 4; ++j) { partf[wv][j] = v[j]; parti[wv][j] = ix[j]; }
    }
    __syncthreads();
    __shared__ float pv0s[4];
    if (t < 4) {
        const int j = t;
        float bv = partf[0][j]; int bi = parti[0][j];
        #pragma unroll
        for (int w = 1; w < 4; ++w) {
            const float ov = partf[w][j]; const int oi = parti[w][j];
            if (ov > bv || (ov == bv && oi < bi)) { bv = ov; bi = oi; }
        }
        pv0s[j] = bv; pi0s[j] = bi;
    }
    __syncthreads();

    // ---- argmax pass 2 (mask winner) ----
    #pragma unroll
    for (int j = 0; j < 4; ++j) {
        v[j] = (t == pi0s[j]) ? -INFINITY : p[j];
        ix[j] = t;
    }
    #pragma unroll
    for (int s = 1; s < 64; s <<= 1) {
        #pragma unroll
        for (int j = 0; j < 4; ++j) {
            const float ov = __shfl_xor(v[j], s);
            const int   oi = __shfl_xor(ix[j], s);
            if (ov > v[j] || (ov == v[j] && oi < ix[j])) { v[j] = ov; ix[j] = oi; }
        }
    }
    if (ln == 0) {
        #pragma unroll
        for (int j = 0; j < 4; ++j) { partf[wv][j] = v[j]; parti[wv][j] = ix[j]; }
    }
    __syncthreads();
    if (t < 4) {
        const int j = t;
        float bv = partf[0][j]; int bi = parti[0][j];
        #pragma unroll
        for (int w = 1; w < 4; ++w) {
            const float ov = partf[w][j]; const int oi = parti[w][j];
            if (ov > bv || (ov == bv && oi < bi)) { bv = ov; bi = oi; }
        }
        const int tok = b * 4 + j;
        const float v0 = pv0s[j], v1 = bv;
        const float den = v0 + v1 + 1e-6f;
        tokinfo[tok] = make_float2(v0 / den, v1 / den);
        const int e0 = pi0s[j], e1 = bi;
        const int q0 = atomicAdd(&counts[e0], 1);
        if (q0 < cap) lists[e0 * cap + q0] = tok * 2;
        const int q1 = atomicAdd(&counts[e1], 1);
        if (q1 < cap) lists[e1 * cap + q1] = tok * 2 + 1;
    }
}

// ---------------- K2: grouped expert matvecs --------------------------------
// 256 blocks (one per expert) x 256 threads. W_e staged in LDS once.
__global__ __launch_bounds__(256) void k_expert(
    const float* __restrict__ x, const float* __restrict__ expert_w,
    const int* __restrict__ counts, const int* __restrict__ lists, int cap,
    float* __restrict__ ybuf)
{
    const int e = blockIdx.x;
    const int t = threadIdx.x;
    const int n = min(counts[e], cap);
    if (n == 0) return;

    __shared__ float W[kD * kD];   // 64 KB
    __shared__ float xs[8][kD];    // 4 KB
    __shared__ int   ent[8];

    const float* Wg = expert_w + (size_t)e * kD * kD;
    #pragma unroll
    for (int k = 0; k < 16; ++k) {
        const int i = k * 256 + t;                     // float4 index
        *(float4*)&W[i * 4] = *(const float4*)&Wg[i * 4];
    }

    const int g = t >> 5, l = t & 31;
    for (int base = 0; base < n; base += 8) {
        if (t < 8 && base + t < n) ent[t] = lists[e * cap + base + t];
        __syncthreads();                                // W ready (1st iter) + ent ready + xs free

        const int idx = base + g;
        const bool valid = idx < n;
        int tok = 0, slot = 0;
        if (valid) {
            const int ev = ent[g];
            tok = ev >> 1; slot = ev & 1;
            *(float4*)&xs[g][l * 4] = *(const float4*)&x[(size_t)tok * kD + l * 4];
        }
        __syncthreads();

        if (valid) {
            float4 a = make_float4(0.f, 0.f, 0.f, 0.f);
            #pragma unroll 4
            for (int d = 0; d < kD; ++d) {
                const float xv = xs[g][d];
                const float4 w4 = *(const float4*)&W[d * kD + l * 4];
                a.x = fmaf(w4.x, xv, a.x);
                a.y = fmaf(w4.y, xv, a.y);
                a.z = fmaf(w4.z, xv, a.z);
                a.w = fmaf(w4.w, xv, a.w);
            }
            *(float4*)&ybuf[((size_t)tok * 2 + slot) * kD + l * 4] = a;
        }
        __syncthreads();                                // protect xs before next overwrite
    }
}

// ---------------- K3: combine + SwiGLU + consensus --------------------------
// 512 blocks x 256 threads; block handles 4 tokens.
__global__ __launch_bounds__(256) void k_swiglu(
    const float* __restrict__ ybuf, const float2* __restrict__ tokinfo,
    const float* __restrict__ w1m, const float* __restrict__ b1,
    const float* __restrict__ w2m, const float* __restrict__ b2,
    float* __restrict__ out_avg, float* __restrict__ out_cons)
{
    const int b = blockIdx.x;
    const int t = threadIdx.x;
    const int tok0 = b * 4;

    __shared__ float  ys[4 * 2 * kD];   // y for 4 tokens x 2 slots
    __shared__ float  wvT[kD][4];       // transposed weighted avg
    __shared__ float  vv[4][kD];        // w2 path
    __shared__ float  os[4][kD];        // final outputs (for variance)
    __shared__ float2 ti[4];

    *(float4*)&ys[t * 4] = *(const float4*)&ybuf[(size_t)tok0 * 2 * kD + t * 4];
    if (t < 4) ti[t] = tokinfo[tok0 + t];
    __syncthreads();

    #pragma unroll
    for (int k = 0; k < 2; ++k) {
        const int idx = t * 2 + k;              // 0..511
        const int j = idx >> 7, o = idx & 127;
        const float2 w = ti[j];
        wvT[o][j] = w.x * ys[(j * 2 + 0) * kD + o] + w.y * ys[(j * 2 + 1) * kD + o];
    }
    __syncthreads();

    const int h = t >> 7, o = t & 127;
    const float* Wm = h ? w2m : w1m;
    const float bias = h ? b2[o] : b1[o];
    float a0 = bias, a1 = bias, a2 = bias, a3 = bias;
    #pragma unroll 4
    for (int d = 0; d < kD; ++d) {
        const float w = Wm[d * kD + o];
        const float4 xv = *(const float4*)&wvT[d][0];
        a0 = fmaf(xv.x, w, a0);
        a1 = fmaf(xv.y, w, a1);
        a2 = fmaf(xv.z, w, a2);
        a3 = fmaf(xv.w, w, a3);
    }
    if (h) { vv[0][o] = a0; vv[1][o] = a1; vv[2][o] = a2; vv[3][o] = a3; }
    __syncthreads();
    if (!h) {
        float gg[4] = {a0, a1, a2, a3};
        #pragma unroll
        for (int j = 0; j < 4; ++j) {
            const float g = gg[j];
            const float r = g * (1.f / (1.f + __expf(-g))) * vv[j][o];
            os[j][o] = r;
            out_avg[(size_t)(tok0 + j) * kD + o] = r;
        }
    }
    __syncthreads();

    // variance -> consensus: wave wv handles token wv (2 outputs/lane)
    const int wv = t >> 6, ln = t & 63;
    const float2 w = ti[wv];
    float s = 0.f;
    #pragma unroll
    for (int k = 0; k < 2; ++k) {
        const int oo = ln * 2 + k;
        const float ot = os[wv][oo];
        const float d0 = ys[(wv * 2 + 0) * kD + oo] - ot;
        const float d1 = ys[(wv * 2 + 1) * kD + oo] - ot;
        s += w.x * d0 * d0 + w.y * d1 * d1;
    }
    #pragma unroll
    for (int sft = 1; sft < 64; sft <<= 1) s += __shfl_xor(s, sft);
    if (ln == 0) out_cons[tok0 + wv] = __expf(-s * (1.0f / (float)kD));
}

extern "C" void kernel_launch(void* const* d_in, const int* in_sizes, int n_in,
                              void* d_out, int out_size, void* d_ws, size_t ws_size,
                              hipStream_t stream) {
    const float*  x        = (const float*)d_in[0];
    const float*  gate_w   = (const float*)d_in[1];
    const float*  gate_b   = (const float*)d_in[2];
    const float*  expert_w = (const float*)d_in[3];
    const float*  w1m      = (const float*)d_in[4];
    const float*  b1       = (const float*)d_in[5];
    const float*  w2m      = (const float*)d_in[6];
    const float*  b2       = (const float*)d_in[7];

    float* out_avg  = (float*)d_out;
    float* out_cons = out_avg + (size_t)kTok * kD;

    char*   ws      = (char*)d_ws;
    int*    counts  = (int*)ws;                                   // 1 KB
    float2* tokinfo = (float2*)(ws + 4096);                       // 16 KB
    float*  ybuf    = (float*)(ws + 32768);                       // 2 MB
    const size_t ybytes = sizeof(float) * (size_t)kTok * 2 * kD;
    int*    lists   = (int*)(ws + 32768 + ybytes);
    const size_t used = 32768 + ybytes;
    size_t avail = (ws_size > used) ? (ws_size - used) / (kE * sizeof(int)) : 0;
    const int cap = (int)((avail > (size_t)kTok) ? (size_t)kTok : avail);

    hipMemsetAsync(counts, 0, kE * sizeof(int), stream);
    k_gate  <<<kTok / 4, 256, 0, stream>>>(x, gate_w, gate_b, tokinfo, counts, lists, cap);
    k_expert<<<kE,       256, 0, stream>>>(x, expert_w, counts, lists, cap, ybuf);
    k_swiglu<<<kTok / 4, 256, 0, stream>>>(ybuf, tokinfo, w1m, b1, w2m, b2, out_avg, out_cons);
}

// Round 3
// 50.355 us; speedup vs baseline: 1.1386x; 1.1386x over previous
//
#include <hip/hip_runtime.h>
#include <math.h>

constexpr int kD   = 128;
constexpr int kE   = 256;
constexpr int kTok = 2048;

// ---------------- K1: gate (logits -> softmax -> top2) ----------------------
// 512 blocks x 256 threads; block handles 4 tokens; thread t = expert t.
__global__ __launch_bounds__(256) void k_gate(
    const float* __restrict__ x, const float* __restrict__ gate_w,
    const float* __restrict__ gate_b,
    float2* __restrict__ tokinfo, int* __restrict__ top2)
{
    const int b  = blockIdx.x;
    const int t  = threadIdx.x;
    const int wv = t >> 6, ln = t & 63;

    __shared__ float xsT[kD][4];      // transposed x tile
    __shared__ float partf[4][4];     // [wave][token]
    __shared__ int   parti[4][4];
    __shared__ int   pi0s[4];
    __shared__ float pv0s[4];

    // wave wv loads token wv's row (float2 per lane)
    {
        const float2 v = *(const float2*)(x + ((size_t)(b * 4 + wv)) * kD + ln * 2);
        xsT[ln * 2 + 0][wv] = v.x;
        xsT[ln * 2 + 1][wv] = v.y;
    }
    __syncthreads();

    // logits: 4 tokens per thread
    float lg[4];
    {
        const float bias = gate_b[t];
        lg[0] = lg[1] = lg[2] = lg[3] = bias;
    }
    #pragma unroll 8
    for (int d = 0; d < kD; ++d) {
        const float w = gate_w[d * kE + t];
        const float4 xv = *(const float4*)&xsT[d][0];
        lg[0] = fmaf(xv.x, w, lg[0]);
        lg[1] = fmaf(xv.y, w, lg[1]);
        lg[2] = fmaf(xv.z, w, lg[2]);
        lg[3] = fmaf(xv.w, w, lg[3]);
    }

    // ---- max over 256 experts ----
    float m[4];
    #pragma unroll
    for (int j = 0; j < 4; ++j) m[j] = lg[j];
    #pragma unroll
    for (int s = 1; s < 64; s <<= 1) {
        #pragma unroll
        for (int j = 0; j < 4; ++j) m[j] = fmaxf(m[j], __shfl_xor(m[j], s));
    }
    if (ln == 0) {
        #pragma unroll
        for (int j = 0; j < 4; ++j) partf[wv][j] = m[j];
    }
    __syncthreads();
    float mx[4];
    #pragma unroll
    for (int j = 0; j < 4; ++j)
        mx[j] = fmaxf(fmaxf(partf[0][j], partf[1][j]), fmaxf(partf[2][j], partf[3][j]));
    __syncthreads();

    // ---- sum of exp ----
    float ex[4], sm[4];
    #pragma unroll
    for (int j = 0; j < 4; ++j) { ex[j] = __expf(lg[j] - mx[j]); sm[j] = ex[j]; }
    #pragma unroll
    for (int s = 1; s < 64; s <<= 1) {
        #pragma unroll
        for (int j = 0; j < 4; ++j) sm[j] += __shfl_xor(sm[j], s);
    }
    if (ln == 0) {
        #pragma unroll
        for (int j = 0; j < 4; ++j) partf[wv][j] = sm[j];
    }
    __syncthreads();
    float p[4];
    #pragma unroll
    for (int j = 0; j < 4; ++j) {
        const float tot = partf[0][j] + partf[1][j] + partf[2][j] + partf[3][j];
        p[j] = ex[j] / tot;
    }
    __syncthreads();

    // ---- argmax pass 1 (ties -> lower index) ----
    float v[4]; int ix[4];
    #pragma unroll
    for (int j = 0; j < 4; ++j) { v[j] = p[j]; ix[j] = t; }
    #pragma unroll
    for (int s = 1; s < 64; s <<= 1) {
        #pragma unroll
        for (int j = 0; j < 4; ++j) {
            const float ov = __shfl_xor(v[j], s);
            const int   oi = __shfl_xor(ix[j], s);
            if (ov > v[j] || (ov == v[j] && oi < ix[j])) { v[j] = ov; ix[j] = oi; }
        }
    }
    if (ln == 0) {
        #pragma unroll
        for (int j = 0; j < 4; ++j) { partf[wv][j] = v[j]; parti[wv][j] = ix[j]; }
    }
    __syncthreads();
    if (t < 4) {
        const int j = t;
        float bv = partf[0][j]; int bi = parti[0][j];
        #pragma unroll
        for (int w = 1; w < 4; ++w) {
            const float ov = partf[w][j]; const int oi = parti[w][j];
            if (ov > bv || (ov == bv && oi < bi)) { bv = ov; bi = oi; }
        }
        pv0s[j] = bv; pi0s[j] = bi;
    }
    __syncthreads();

    // ---- argmax pass 2 (mask winner) ----
    #pragma unroll
    for (int j = 0; j < 4; ++j) {
        v[j] = (t == pi0s[j]) ? -INFINITY : p[j];
        ix[j] = t;
    }
    #pragma unroll
    for (int s = 1; s < 64; s <<= 1) {
        #pragma unroll
        for (int j = 0; j < 4; ++j) {
            const float ov = __shfl_xor(v[j], s);
            const int   oi = __shfl_xor(ix[j], s);
            if (ov > v[j] || (ov == v[j] && oi < ix[j])) { v[j] = ov; ix[j] = oi; }
        }
    }
    if (ln == 0) {
        #pragma unroll
        for (int j = 0; j < 4; ++j) { partf[wv][j] = v[j]; parti[wv][j] = ix[j]; }
    }
    __syncthreads();
    if (t < 4) {
        const int j = t;
        float bv = partf[0][j]; int bi = parti[0][j];
        #pragma unroll
        for (int w = 1; w < 4; ++w) {
            const float ov = partf[w][j]; const int oi = parti[w][j];
            if (ov > bv || (ov == bv && oi < bi)) { bv = ov; bi = oi; }
        }
        const int tok = b * 4 + j;
        const float v0 = pv0s[j], v1 = bv;
        const float den = v0 + v1 + 1e-6f;
        tokinfo[tok] = make_float2(v0 / den, v1 / den);
        top2[tok] = pi0s[j] | (bi << 8);    // e0 | e1<<8
    }
}

// ---------------- K2: grouped expert matvecs --------------------------------
// 256 blocks (one per expert) x 256 threads. Each block scans top2[] to build
// its token list in LDS (local atomic, nothing to zero globally), stages W_e
// in LDS once, then does grouped matvecs.
__global__ __launch_bounds__(256) void k_expert(
    const float* __restrict__ x, const float* __restrict__ expert_w,
    const int* __restrict__ top2, float* __restrict__ ybuf)
{
    const int e = blockIdx.x;
    const int t = threadIdx.x;

    __shared__ float W[kD * kD];   // 64 KB
    __shared__ float xs[8][kD];    // 4 KB
    __shared__ int   llist[kTok];  // 8 KB (worst case)
    __shared__ int   lcount;

    if (t == 0) lcount = 0;
    __syncthreads();

    // scan token routing (8 KB, L2-resident) -> local list
    for (int i = t; i < kTok; i += 256) {
        const int pk = top2[i];
        if ((pk & 0xFF) == e)        llist[atomicAdd(&lcount, 1)] = i * 2;
        if (((pk >> 8) & 0xFF) == e) llist[atomicAdd(&lcount, 1)] = i * 2 + 1;
    }

    // stage expert weights
    const float* Wg = expert_w + (size_t)e * kD * kD;
    #pragma unroll
    for (int k = 0; k < 16; ++k) {
        const int i4 = k * 256 + t;
        *(float4*)&W[i4 * 4] = *(const float4*)&Wg[i4 * 4];
    }
    __syncthreads();
    const int n = lcount;

    const int g = t >> 5, l = t & 31;
    for (int base = 0; base < n; base += 8) {
        const int idx = base + g;
        const bool valid = idx < n;
        int tok = 0, slot = 0;
        if (valid) {
            const int ev = llist[idx];
            tok = ev >> 1; slot = ev & 1;
            *(float4*)&xs[g][l * 4] = *(const float4*)&x[(size_t)tok * kD + l * 4];
        }
        __syncthreads();

        if (valid) {
            float4 a = make_float4(0.f, 0.f, 0.f, 0.f);
            #pragma unroll 4
            for (int d = 0; d < kD; ++d) {
                const float xv = xs[g][d];
                const float4 w4 = *(const float4*)&W[d * kD + l * 4];
                a.x = fmaf(w4.x, xv, a.x);
                a.y = fmaf(w4.y, xv, a.y);
                a.z = fmaf(w4.z, xv, a.z);
                a.w = fmaf(w4.w, xv, a.w);
            }
            *(float4*)&ybuf[((size_t)tok * 2 + slot) * kD + l * 4] = a;
        }
        __syncthreads();
    }
}

// ---------------- K3: combine + SwiGLU + consensus --------------------------
// 512 blocks x 256 threads; block handles 4 tokens.
__global__ __launch_bounds__(256) void k_swiglu(
    const float* __restrict__ ybuf, const float2* __restrict__ tokinfo,
    const float* __restrict__ w1m, const float* __restrict__ b1,
    const float* __restrict__ w2m, const float* __restrict__ b2,
    float* __restrict__ out_avg, float* __restrict__ out_cons)
{
    const int b = blockIdx.x;
    const int t = threadIdx.x;
    const int tok0 = b * 4;

    __shared__ float  ys[4 * 2 * kD];   // y for 4 tokens x 2 slots
    __shared__ float  wvT[kD][4];       // transposed weighted avg
    __shared__ float  vv[4][kD];        // w2 path
    __shared__ float  os[4][kD];        // final outputs (for variance)
    __shared__ float2 ti[4];

    *(float4*)&ys[t * 4] = *(const float4*)&ybuf[(size_t)tok0 * 2 * kD + t * 4];
    if (t < 4) ti[t] = tokinfo[tok0 + t];
    __syncthreads();

    #pragma unroll
    for (int k = 0; k < 2; ++k) {
        const int idx = t * 2 + k;              // 0..511
        const int j = idx >> 7, o = idx & 127;
        const float2 w = ti[j];
        wvT[o][j] = w.x * ys[(j * 2 + 0) * kD + o] + w.y * ys[(j * 2 + 1) * kD + o];
    }
    __syncthreads();

    const int h = t >> 7, o = t & 127;
    const float* Wm = h ? w2m : w1m;
    const float bias = h ? b2[o] : b1[o];
    float a0 = bias, a1 = bias, a2 = bias, a3 = bias;
    #pragma unroll 4
    for (int d = 0; d < kD; ++d) {
        const float w = Wm[d * kD + o];
        const float4 xv = *(const float4*)&wvT[d][0];
        a0 = fmaf(xv.x, w, a0);
        a1 = fmaf(xv.y, w, a1);
        a2 = fmaf(xv.z, w, a2);
        a3 = fmaf(xv.w, w, a3);
    }
    if (h) { vv[0][o] = a0; vv[1][o] = a1; vv[2][o] = a2; vv[3][o] = a3; }
    __syncthreads();
    if (!h) {
        float gg[4] = {a0, a1, a2, a3};
        #pragma unroll
        for (int j = 0; j < 4; ++j) {
            const float g = gg[j];
            const float r = g * (1.f / (1.f + __expf(-g))) * vv[j][o];
            os[j][o] = r;
            out_avg[(size_t)(tok0 + j) * kD + o] = r;
        }
    }
    __syncthreads();

    // variance -> consensus: wave wv handles token wv (2 outputs/lane)
    const int wv = t >> 6, ln = t & 63;
    const float2 w = ti[wv];
    float s = 0.f;
    #pragma unroll
    for (int k = 0; k < 2; ++k) {
        const int oo = ln * 2 + k;
        const float ot = os[wv][oo];
        const float d0 = ys[(wv * 2 + 0) * kD + oo] - ot;
        const float d1 = ys[(wv * 2 + 1) * kD + oo] - ot;
        s += w.x * d0 * d0 + w.y * d1 * d1;
    }
    #pragma unroll
    for (int sft = 1; sft < 64; sft <<= 1) s += __shfl_xor(s, sft);
    if (ln == 0) out_cons[tok0 + wv] = __expf(-s * (1.0f / (float)kD));
}

extern "C" void kernel_launch(void* const* d_in, const int* in_sizes, int n_in,
                              void* d_out, int out_size, void* d_ws, size_t ws_size,
                              hipStream_t stream) {
    const float*  x        = (const float*)d_in[0];
    const float*  gate_w   = (const float*)d_in[1];
    const float*  gate_b   = (const float*)d_in[2];
    const float*  expert_w = (const float*)d_in[3];
    const float*  w1m      = (const float*)d_in[4];
    const float*  b1       = (const float*)d_in[5];
    const float*  w2m      = (const float*)d_in[6];
    const float*  b2       = (const float*)d_in[7];

    float* out_avg  = (float*)d_out;
    float* out_cons = out_avg + (size_t)kTok * kD;

    char*   ws      = (char*)d_ws;
    float2* tokinfo = (float2*)ws;                 // 16 KB
    int*    top2    = (int*)(ws + 16384);          // 8 KB
    float*  ybuf    = (float*)(ws + 32768);        // 2 MB

    k_gate  <<<kTok / 4, 256, 0, stream>>>(x, gate_w, gate_b, tokinfo, top2);
    k_expert<<<kE,       256, 0, stream>>>(x, expert_w, top2, ybuf);
    k_swiglu<<<kTok / 4, 256, 0, stream>>>(ybuf, tokinfo, w1m, b1, w2m, b2, out_avg, out_cons);
}